// Round 10
// baseline (285.111 us; speedup 1.0000x reference)
//
#include <hip/hip_runtime.h>
#include <hip/hip_bf16.h>
#include <math.h>

#define N_NODES 100000
#define N_EDGES 1600000
#define D_FEAT  64
#define BN_EPS  1e-5f

#define NBUCKET_PAD 256      // padded bucket slots (196 used)
#define BUCKET_SHIFT 9       // 512 nodes per bucket
#define NBLK_E  196          // blocks in edge passes
#define EPB     8192         // edges per block (196*8192 >= E)
#define HIST_TOTAL (NBUCKET_PAD * NBLK_E)   // 50176
#define NCHUNK_H 98          // HIST_TOTAL / 512
#define DCAP    14336        // bucket staging cap (mean 8192, sd ~90)
#define GEMM_BLOCKS 1563     // ceil(N_NODES / 64)

#define GGRID   1024         // gather grid: 4 blocks/CU * 256 CU, co-resident
#define GWAVES  (GGRID * 4)  // 4096
#define NQUADS  (N_NODES / 4)  // 25000
#define GITERS  7            // ceil(NQUADS / GWAVES)

typedef __attribute__((ext_vector_type(8))) short bf16x8;
typedef __attribute__((ext_vector_type(4))) float f32x4;

static __device__ __forceinline__ short f2bf(float f) {
    __hip_bfloat16 h = __float2bfloat16(f);
    return __builtin_bit_cast(short, h);
}

// ws layout (byte offsets):
//   0         : mix plane, [N] rows of 192 B: 64 B q-fp8 + 128 B v-bf16
//               (19,200,000)
//   19200000  : k plane,  [N][64] bf16                      (12,800,000)
//   32000000  : stats fp32[128]                             (512)
//   32000512  : barrier counter int                         (16)
//   32000528  : blockhist int[256*196]                      (200,704)
//   32201232  : chunk_sums int[98] (pad 400)
//   32201632  : chunk_off int[98] (pad 400)
//   32202032  : row_start int[N+1]                          (400,004)
//   32602036  : tmp/sorted_src u32[E] (in-place reuse)      (6,400,000)

// ---------------------------------------------------------------------------
// Kernel 1 (fused): blocks [0,GEMM_BLOCKS) = four bf16 MFMA linears with
// LDS-repacked coalesced epilogue (q -> fp8, v/k -> bf16); blocks
// [GEMM_BLOCKS, +NBLK_E) = edge bucket histogram.
// ---------------------------------------------------------------------------
__global__ __launch_bounds__(256) void gemm4_count_kernel(
    const float* __restrict__ x,
    const float* __restrict__ Wk, const float* __restrict__ bk,
    const float* __restrict__ Wq, const float* __restrict__ bq,
    const float* __restrict__ Wv, const float* __restrict__ bv,
    const float* __restrict__ Ws, const float* __restrict__ bs,
    unsigned char* __restrict__ mix,    // [N] 192-B rows (q fp8 | v bf16)
    unsigned short* __restrict__ kp,    // [N][64] bf16 bits
    float* __restrict__ h0,             // [N][64] fp32 (== d_out)
    const int* __restrict__ ei, int* __restrict__ blockhist)
{
    __shared__ short xs[64 * 64];            // 8 KB staging tile
    __shared__ unsigned short kt[64][68];    // padded repack tiles
    __shared__ unsigned short qt[64][68];
    __shared__ unsigned short vt[64][68];
    __shared__ int hcnt[NBUCKET_PAD];

    // ---------------- bucket-count path ----------------
    if (blockIdx.x >= GEMM_BLOCKS) {
        const int cb = blockIdx.x - GEMM_BLOCKS;
        hcnt[threadIdx.x] = 0;
        __syncthreads();
        const int base = cb * EPB;
        for (int i = threadIdx.x; i < EPB; i += 256) {
            const int e = base + i;
            if (e < N_EDGES) atomicAdd(&hcnt[ei[N_EDGES + e] >> BUCKET_SHIFT], 1);
        }
        __syncthreads();
        blockhist[threadIdx.x * NBLK_E + cb] = hcnt[threadIdx.x];
        return;
    }

    // ---------------- GEMM path ----------------
    const int lane = threadIdx.x & 63;
    const int wave = threadIdx.x >> 6;
    const int r0 = blockIdx.x * 64;

    const float* W; const float* b;
    if      (wave == 0) { W = Wk; b = bk; }
    else if (wave == 1) { W = Wq; b = bq; }
    else if (wave == 2) { W = Wv; b = bv; }
    else                { W = Ws; b = bs; }

    const int bcol = lane & 15;
    const int bk0  = (lane >> 4) * 8;
    bf16x8 bfrag[4][2];
    #pragma unroll
    for (int nt = 0; nt < 4; ++nt) {
        #pragma unroll
        for (int ks = 0; ks < 2; ++ks) {
            const float* wp = W + (nt * 16 + bcol) * 64 + ks * 32 + bk0;
            const float4 w0 = *reinterpret_cast<const float4*>(wp);
            const float4 w1 = *reinterpret_cast<const float4*>(wp + 4);
            bf16x8 f;
            f[0] = f2bf(w0.x); f[1] = f2bf(w0.y); f[2] = f2bf(w0.z); f[3] = f2bf(w0.w);
            f[4] = f2bf(w1.x); f[5] = f2bf(w1.y); f[6] = f2bf(w1.z); f[7] = f2bf(w1.w);
            bfrag[nt][ks] = f;
        }
    }
    float biasv[4];
    #pragma unroll
    for (int nt = 0; nt < 4; ++nt) biasv[nt] = b[nt * 16 + bcol];

    {
        const int row = threadIdx.x >> 2;
        const int qd  = threadIdx.x & 3;
        const int grow = r0 + row;
        float4 t0, t1, t2, t3;
        if (grow < N_NODES) {
            const float* xp = x + (size_t)grow * 64 + qd * 16;
            t0 = reinterpret_cast<const float4*>(xp)[0];
            t1 = reinterpret_cast<const float4*>(xp)[1];
            t2 = reinterpret_cast<const float4*>(xp)[2];
            t3 = reinterpret_cast<const float4*>(xp)[3];
        } else {
            t0 = t1 = t2 = t3 = make_float4(0.f, 0.f, 0.f, 0.f);
        }
        bf16x8 u0, u1;
        u0[0] = f2bf(t0.x); u0[1] = f2bf(t0.y); u0[2] = f2bf(t0.z); u0[3] = f2bf(t0.w);
        u0[4] = f2bf(t1.x); u0[5] = f2bf(t1.y); u0[6] = f2bf(t1.z); u0[7] = f2bf(t1.w);
        u1[0] = f2bf(t2.x); u1[1] = f2bf(t2.y); u1[2] = f2bf(t2.z); u1[3] = f2bf(t2.w);
        u1[4] = f2bf(t3.x); u1[5] = f2bf(t3.y); u1[6] = f2bf(t3.z); u1[7] = f2bf(t3.w);
        const int sw = row & 7;
        *reinterpret_cast<bf16x8*>(xs + row * 64 + (((qd * 2)     ^ sw) * 8)) = u0;
        *reinterpret_cast<bf16x8*>(xs + row * 64 + (((qd * 2 + 1) ^ sw) * 8)) = u1;
    }
    __syncthreads();

    f32x4 acc[4][4];
    #pragma unroll
    for (int mt = 0; mt < 4; ++mt)
        #pragma unroll
        for (int nt = 0; nt < 4; ++nt)
            acc[mt][nt] = (f32x4){biasv[nt], biasv[nt], biasv[nt], biasv[nt]};

    const int arow = lane & 15;
    const int ak   = lane >> 4;
    #pragma unroll
    for (int mt = 0; mt < 4; ++mt) {
        const int row = mt * 16 + arow;
        const int sw = row & 7;
        const bf16x8 a0 = *reinterpret_cast<const bf16x8*>(xs + row * 64 + ((ak       ^ sw) * 8));
        const bf16x8 a1 = *reinterpret_cast<const bf16x8*>(xs + row * 64 + (((4 + ak) ^ sw) * 8));
        #pragma unroll
        for (int nt = 0; nt < 4; ++nt) {
            acc[mt][nt] = __builtin_amdgcn_mfma_f32_16x16x32_bf16(
                a0, bfrag[nt][0], acc[mt][nt], 0, 0, 0);
            acc[mt][nt] = __builtin_amdgcn_mfma_f32_16x16x32_bf16(
                a1, bfrag[nt][1], acc[mt][nt], 0, 0, 0);
        }
    }

    // epilogue: waves 0/1/2 stash bf16 results in LDS; wave 3 stores h0 fp32.
    const int crow0 = (lane >> 4) * 4;
    const int ccol  = lane & 15;
    if (wave < 3) {
        unsigned short (*tile)[68] = (wave == 0) ? kt : (wave == 1) ? qt : vt;
        #pragma unroll
        for (int mt = 0; mt < 4; ++mt)
            #pragma unroll
            for (int nt = 0; nt < 4; ++nt)
                #pragma unroll
                for (int r = 0; r < 4; ++r)
                    tile[mt * 16 + crow0 + r][nt * 16 + ccol] =
                        (unsigned short)f2bf(acc[mt][nt][r]);
    } else {
        #pragma unroll
        for (int mt = 0; mt < 4; ++mt)
            #pragma unroll
            for (int nt = 0; nt < 4; ++nt)
                #pragma unroll
                for (int r = 0; r < 4; ++r) {
                    const int grow = r0 + mt * 16 + crow0 + r;
                    if (grow < N_NODES)
                        h0[(size_t)grow * 64 + nt * 16 + ccol] = acc[mt][nt][r];
                }
    }
    __syncthreads();

    // cooperative coalesced flush: thread -> (row, 16-feature segment)
    {
        const int row = threadIdx.x >> 2;
        const int seg = threadIdx.x & 3;
        const int grow = r0 + row;
        if (grow < N_NODES) {
            const int c0 = seg * 16;
            unsigned char* mrow = mix + (size_t)grow * 192;

            // q -> fp8 e4m3 (16 B per seg)
            unsigned int qd[4];
            #pragma unroll
            for (int i = 0; i < 4; ++i) {
                const float f0 = __uint_as_float((unsigned int)qt[row][c0 + 4*i + 0] << 16);
                const float f1 = __uint_as_float((unsigned int)qt[row][c0 + 4*i + 1] << 16);
                const float f2 = __uint_as_float((unsigned int)qt[row][c0 + 4*i + 2] << 16);
                const float f3 = __uint_as_float((unsigned int)qt[row][c0 + 4*i + 3] << 16);
                int p = __builtin_amdgcn_cvt_pk_fp8_f32(f0, f1, 0, false);
                p = __builtin_amdgcn_cvt_pk_fp8_f32(f2, f3, p, true);
                qd[i] = (unsigned int)p;
            }
            *reinterpret_cast<uint4*>(mrow + c0) =
                make_uint4(qd[0], qd[1], qd[2], qd[3]);

            // v -> bf16 (32 B per seg)
            unsigned int vd[8];
            #pragma unroll
            for (int i = 0; i < 8; ++i)
                vd[i] = (unsigned int)vt[row][c0 + 2 * i] |
                        ((unsigned int)vt[row][c0 + 2 * i + 1] << 16);
            uint4* vdst = reinterpret_cast<uint4*>(mrow + 64 + seg * 32);
            vdst[0] = make_uint4(vd[0], vd[1], vd[2], vd[3]);
            vdst[1] = make_uint4(vd[4], vd[5], vd[6], vd[7]);

            // k -> bf16 plane (32 B per seg)
            unsigned int kd[8];
            #pragma unroll
            for (int i = 0; i < 8; ++i)
                kd[i] = (unsigned int)kt[row][c0 + 2 * i] |
                        ((unsigned int)kt[row][c0 + 2 * i + 1] << 16);
            uint4* kdst = reinterpret_cast<uint4*>(kp + (size_t)grow * 64 + c0);
            kdst[0] = make_uint4(kd[0], kd[1], kd[2], kd[3]);
            kdst[1] = make_uint4(kd[4], kd[5], kd[6], kd[7]);
        }
    }
}

// ---------------------------------------------------------------------------
// CSR build. scan3 folded into bucket_scatter / bucket_sort.
// ---------------------------------------------------------------------------
__global__ __launch_bounds__(256) void scan1_kernel(
    int* __restrict__ buf, int* __restrict__ chunk_sums, int total)
{
    __shared__ int sh[256];
    const int t = threadIdx.x;
    const int base = blockIdx.x * 512;
    const int i0 = base + 2 * t, i1 = base + 2 * t + 1;
    const int a = (i0 < total) ? buf[i0] : 0;
    const int b = (i1 < total) ? buf[i1] : 0;
    const int s = a + b;
    sh[t] = s;
    __syncthreads();
    for (int off = 1; off < 256; off <<= 1) {
        const int val = (t >= off) ? sh[t - off] : 0;
        __syncthreads();
        sh[t] += val;
        __syncthreads();
    }
    const int excl = sh[t] - s;
    if (i0 < total) buf[i0] = excl;
    if (i1 < total) buf[i1] = excl + a;
    if (t == 255) chunk_sums[blockIdx.x] = sh[255];
}

__global__ __launch_bounds__(256) void scan2_kernel(
    const int* __restrict__ chunk_sums, int* __restrict__ chunk_off, int nchunk)
{
    __shared__ int sh[256];
    const int t = threadIdx.x;
    const int v = (t < nchunk) ? chunk_sums[t] : 0;
    sh[t] = v;
    __syncthreads();
    for (int off = 1; off < 256; off <<= 1) {
        const int val = (t >= off) ? sh[t - off] : 0;
        __syncthreads();
        sh[t] += val;
        __syncthreads();
    }
    if (t < nchunk) chunk_off[t] = sh[t] - v;
}

__global__ __launch_bounds__(256) void bucket_scatter_kernel(
    const int* __restrict__ ei, const int* __restrict__ blockhist,
    const int* __restrict__ chunk_off, unsigned int* __restrict__ tmp)
{
    __shared__ int cur[NBUCKET_PAD];
    {
        const int idx = threadIdx.x * NBLK_E + blockIdx.x;
        cur[threadIdx.x] = blockhist[idx] + chunk_off[idx >> 9];
    }
    __syncthreads();
    const int base = blockIdx.x * EPB;
    for (int i = threadIdx.x; i < EPB; i += 256) {
        const int e = base + i;
        if (e < N_EDGES) {
            const int s = ei[e];
            const int d = ei[N_EDGES + e];
            const int pos = atomicAdd(&cur[d >> BUCKET_SHIFT], 1);
            tmp[pos] = ((unsigned int)s << BUCKET_SHIFT) | (unsigned int)(d & 511);
        }
    }
}

__global__ __launch_bounds__(512) void bucket_sort_kernel(
    const int* __restrict__ blockhist, const int* __restrict__ chunk_off,
    unsigned int* __restrict__ tmp,
    int* __restrict__ row_start)
{
    __shared__ unsigned int stage[DCAP];
    __shared__ int hist[512];
    __shared__ int cursor[512];
    const int b = blockIdx.x;
    const int t = threadIdx.x;
    const int ia = b * NBLK_E;
    const int ib = (b + 1) * NBLK_E;
    const int bstart = blockhist[ia] + chunk_off[ia >> 9];
    const int bend   = blockhist[ib] + chunk_off[ib >> 9];
    int sz = bend - bstart;
    if (sz > DCAP) sz = DCAP;
    for (int i = t; i < sz; i += 512) stage[i] = tmp[bstart + i];
    hist[t] = 0;
    __syncthreads();
    for (int i = t; i < sz; i += 512) atomicAdd(&hist[stage[i] & 511], 1);
    __syncthreads();
    const int myv = hist[t];
    for (int off = 1; off < 512; off <<= 1) {
        const int u = (t >= off) ? hist[t - off] : 0;
        __syncthreads();
        hist[t] += u;
        __syncthreads();
    }
    const int excl = hist[t] - myv;
    const int node = b * 512 + t;
    if (node <= N_NODES) row_start[node] = bstart + excl;
    cursor[t] = excl;
    __syncthreads();
    for (int i = t; i < sz; i += 512) {
        const unsigned int pk = stage[i];
        const int pos = atomicAdd(&cursor[(int)(pk & 511)], 1);
        tmp[bstart + pos] = pk >> BUCKET_SHIFT;
    }
}

// ---------------------------------------------------------------------------
// Gather + BN + ReLU + residual, fused via software grid barrier.
// Persistent: 1024 blocks (4/CU guaranteed by __launch_bounds__(256,4)).
// Phase A: gather edges into register acc[7]; accumulate BN stats.
// Barrier: device-scope atomic counter + s_sleep spin.
// Phase B: read stats coherently, normalize acc from registers, +x, write h0.
// ---------------------------------------------------------------------------
static __device__ __forceinline__ void edge4(
    float4& acc, const float4& kf, unsigned int qb, uint2 vb)
{
    const float q0 = __builtin_amdgcn_cvt_f32_fp8(qb, 0);
    const float q1 = __builtin_amdgcn_cvt_f32_fp8(qb, 1);
    const float q2 = __builtin_amdgcn_cvt_f32_fp8(qb, 2);
    const float q3 = __builtin_amdgcn_cvt_f32_fp8(qb, 3);
    const float v0 = __uint_as_float(vb.x << 16);
    const float v1 = __uint_as_float(vb.x & 0xffff0000u);
    const float v2 = __uint_as_float(vb.y << 16);
    const float v3 = __uint_as_float(vb.y & 0xffff0000u);
    acc.x = fmaf(__builtin_amdgcn_rcpf(1.0f + __expf(-(kf.x + q0))), v0, acc.x);
    acc.y = fmaf(__builtin_amdgcn_rcpf(1.0f + __expf(-(kf.y + q1))), v1, acc.y);
    acc.z = fmaf(__builtin_amdgcn_rcpf(1.0f + __expf(-(kf.z + q2))), v2, acc.z);
    acc.w = fmaf(__builtin_amdgcn_rcpf(1.0f + __expf(-(kf.w + q3))), v3, acc.w);
}

__global__ __launch_bounds__(256, 4) void gather_final_kernel(
    const unsigned char* __restrict__ mix,
    const unsigned short* __restrict__ kp,
    const int* __restrict__ row_start,
    const int* __restrict__ sorted_src,
    float* __restrict__ h0,
    const float* __restrict__ x,
    const float* __restrict__ gamma, const float* __restrict__ beta,
    float* __restrict__ stats, int* __restrict__ counter)
{
    const int lane = threadIdx.x & 63;
    const int sub  = lane >> 4;
    const int l    = lane & 15;
    const int wave = threadIdx.x >> 6;
    const int wave_id = blockIdx.x * 4 + wave;

    __shared__ float bsum[64];
    __shared__ float bsq[64];
    __shared__ float sstat[128];

    float4 lsum = make_float4(0.f, 0.f, 0.f, 0.f);
    float4 lsq  = make_float4(0.f, 0.f, 0.f, 0.f);
    float4 acc[GITERS];

    // ---------------- Phase A: gather + stats ----------------
    #pragma unroll
    for (int i = 0; i < GITERS; ++i) {
        acc[i] = make_float4(0.f, 0.f, 0.f, 0.f);
        const int quad = wave_id + i * GWAVES;
        if (quad < NQUADS) {
            const int n = quad * 4 + sub;
            const int base = row_start[n];
            const int end  = row_start[n + 1];
            const int deg  = end - base;

            int m1 = max(deg, __shfl_xor(deg, 16));
            const int maxdeg = max(m1, __shfl_xor(m1, 32));

            const ushort4 kr = *reinterpret_cast<const ushort4*>(kp + (size_t)n * 64 + 4 * l);
            float4 kf;
            kf.x = __uint_as_float((unsigned int)kr.x << 16);
            kf.y = __uint_as_float((unsigned int)kr.y << 16);
            kf.z = __uint_as_float((unsigned int)kr.z << 16);
            kf.w = __uint_as_float((unsigned int)kr.w << 16);
            acc[i] = *reinterpret_cast<const float4*>(h0 + (size_t)n * 64 + 4 * l);

            const int safe_last = max(min(end - 1, N_EDGES - 1), 0);

            for (int t = 0; t < maxdeg; t += 4) {
                const int i0 = min(base + t + 0, safe_last);
                const int i1 = min(base + t + 1, safe_last);
                const int i2 = min(base + t + 2, safe_last);
                const int i3 = min(base + t + 3, safe_last);
                const size_t r0 = (size_t)sorted_src[i0] * 192;
                const size_t r1 = (size_t)sorted_src[i1] * 192;
                const size_t r2 = (size_t)sorted_src[i2] * 192;
                const size_t r3 = (size_t)sorted_src[i3] * 192;
                const unsigned int qb0 = *reinterpret_cast<const unsigned int*>(mix + r0 + 4 * l);
                const unsigned int qb1 = *reinterpret_cast<const unsigned int*>(mix + r1 + 4 * l);
                const unsigned int qb2 = *reinterpret_cast<const unsigned int*>(mix + r2 + 4 * l);
                const unsigned int qb3 = *reinterpret_cast<const unsigned int*>(mix + r3 + 4 * l);
                uint2 vb0 = *reinterpret_cast<const uint2*>(mix + r0 + 64 + 8 * l);
                uint2 vb1 = *reinterpret_cast<const uint2*>(mix + r1 + 64 + 8 * l);
                uint2 vb2 = *reinterpret_cast<const uint2*>(mix + r2 + 64 + 8 * l);
                uint2 vb3 = *reinterpret_cast<const uint2*>(mix + r3 + 64 + 8 * l);
                const bool m0 = (t + 0) < deg, m1b = (t + 1) < deg,
                           m2 = (t + 2) < deg, m3 = (t + 3) < deg;
                vb0.x = m0 ? vb0.x : 0u;  vb0.y = m0 ? vb0.y : 0u;
                vb1.x = m1b ? vb1.x : 0u; vb1.y = m1b ? vb1.y : 0u;
                vb2.x = m2 ? vb2.x : 0u;  vb2.y = m2 ? vb2.y : 0u;
                vb3.x = m3 ? vb3.x : 0u;  vb3.y = m3 ? vb3.y : 0u;

                edge4(acc[i], kf, qb0, vb0);
                edge4(acc[i], kf, qb1, vb1);
                edge4(acc[i], kf, qb2, vb2);
                edge4(acc[i], kf, qb3, vb3);
            }

            lsum.x += acc[i].x; lsum.y += acc[i].y;
            lsum.z += acc[i].z; lsum.w += acc[i].w;
            lsq.x += acc[i].x * acc[i].x; lsq.y += acc[i].y * acc[i].y;
            lsq.z += acc[i].z * acc[i].z; lsq.w += acc[i].w * acc[i].w;
        }
    }

    // block-level stats reduce -> global atomics
    if (threadIdx.x < 64) { bsum[threadIdx.x] = 0.f; bsq[threadIdx.x] = 0.f; }
    __syncthreads();
    atomicAdd(&bsum[4 * l + 0], lsum.x); atomicAdd(&bsq[4 * l + 0], lsq.x);
    atomicAdd(&bsum[4 * l + 1], lsum.y); atomicAdd(&bsq[4 * l + 1], lsq.y);
    atomicAdd(&bsum[4 * l + 2], lsum.z); atomicAdd(&bsq[4 * l + 2], lsq.z);
    atomicAdd(&bsum[4 * l + 3], lsum.w); atomicAdd(&bsq[4 * l + 3], lsq.w);
    __syncthreads();
    if (threadIdx.x < 64) {
        atomicAdd(&stats[threadIdx.x], bsum[threadIdx.x]);
        atomicAdd(&stats[64 + threadIdx.x], bsq[threadIdx.x]);
    }

    // ---------------- software grid barrier ----------------
    __syncthreads();   // drains the stats atomics (vmcnt(0) before s_barrier)
    if (threadIdx.x == 0) {
        __threadfence();
        atomicAdd(counter, 1);
        while (atomicAdd(counter, 0) < GGRID) {
            __builtin_amdgcn_s_sleep(32);
        }
    }
    __syncthreads();

    // ---------------- Phase B: normalize from registers ----------------
    // coherent stats read (device-scope atomic load beats stale L1/L2)
    if (threadIdx.x < 128)
        sstat[threadIdx.x] = atomicAdd(&stats[threadIdx.x], 0.0f);
    __syncthreads();

    const float invN = 1.0f / (float)N_NODES;
    const float4 g  = *reinterpret_cast<const float4*>(gamma + 4 * l);
    const float4 bt = *reinterpret_cast<const float4*>(beta + 4 * l);
    float4 mean, a;
    mean.x = sstat[4 * l + 0] * invN; mean.y = sstat[4 * l + 1] * invN;
    mean.z = sstat[4 * l + 2] * invN; mean.w = sstat[4 * l + 3] * invN;
    a.x = rsqrtf(sstat[64 + 4 * l + 0] * invN - mean.x * mean.x + BN_EPS) * g.x;
    a.y = rsqrtf(sstat[64 + 4 * l + 1] * invN - mean.y * mean.y + BN_EPS) * g.y;
    a.z = rsqrtf(sstat[64 + 4 * l + 2] * invN - mean.z * mean.z + BN_EPS) * g.z;
    a.w = rsqrtf(sstat[64 + 4 * l + 3] * invN - mean.w * mean.w + BN_EPS) * g.w;

    #pragma unroll
    for (int i = 0; i < GITERS; ++i) {
        const int quad = wave_id + i * GWAVES;
        if (quad < NQUADS) {
            const int n = quad * 4 + sub;
            const size_t off = (size_t)n * 64 + 4 * l;
            const float4 xx = *reinterpret_cast<const float4*>(x + off);
            float4 y;
            y.x = fmaxf((acc[i].x - mean.x) * a.x + bt.x, 0.f) + xx.x;
            y.y = fmaxf((acc[i].y - mean.y) * a.y + bt.y, 0.f) + xx.y;
            y.z = fmaxf((acc[i].z - mean.z) * a.z + bt.z, 0.f) + xx.z;
            y.w = fmaxf((acc[i].w - mean.w) * a.w + bt.w, 0.f) + xx.w;
            *reinterpret_cast<float4*>(h0 + off) = y;
        }
    }
}

// ---------------------------------------------------------------------------
extern "C" void kernel_launch(void* const* d_in, const int* in_sizes, int n_in,
                              void* d_out, int out_size, void* d_ws, size_t ws_size,
                              hipStream_t stream)
{
    const float* x     = (const float*)d_in[0];
    const int*   ei    = (const int*)d_in[1];
    const float* Wk    = (const float*)d_in[2];
    const float* bk    = (const float*)d_in[3];
    const float* Wq    = (const float*)d_in[4];
    const float* bq    = (const float*)d_in[5];
    const float* Wv    = (const float*)d_in[6];
    const float* bv    = (const float*)d_in[7];
    const float* Ws    = (const float*)d_in[8];
    const float* bs    = (const float*)d_in[9];
    const float* gamma = (const float*)d_in[10];
    const float* beta  = (const float*)d_in[11];

    char* w = (char*)d_ws;
    unsigned char*  mix  = (unsigned char*)w;               // 19.2 MB
    unsigned short* kpl  = (unsigned short*)(w + 19200000); // 12.8 MB
    float* stats      = (float*)(w + 32000000);             // 512 B
    int*   counter    = (int*)  (w + 32000512);             // 16 B
    int*   blockhist  = (int*)  (w + 32000528);
    int*   chunk_sums = (int*)  (w + 32201232);
    int*   chunk_off  = (int*)  (w + 32201632);
    int*   row_start  = (int*)  (w + 32202032);
    unsigned int* tmp = (unsigned int*)(w + 32602036);

    float* h0 = (float*)d_out;

    // zero stats + barrier counter in one capturable memset
    hipMemsetAsync(stats, 0, 528, stream);

    // fused: MFMA linears (blocks 0..1562) + bucket histogram (blocks 1563..1758)
    gemm4_count_kernel<<<GEMM_BLOCKS + NBLK_E, 256, 0, stream>>>(
        x, Wk, bk, Wq, bq, Wv, bv, Ws, bs, mix, kpl, h0, ei, blockhist);

    scan1_kernel<<<NCHUNK_H, 256, 0, stream>>>(blockhist, chunk_sums, HIST_TOTAL);
    scan2_kernel<<<1, 256, 0, stream>>>(chunk_sums, chunk_off, NCHUNK_H);
    bucket_scatter_kernel<<<NBLK_E, 256, 0, stream>>>(ei, blockhist, chunk_off, tmp);
    bucket_sort_kernel<<<196, 512, 0, stream>>>(blockhist, chunk_off, tmp, row_start);

    // fused gather + BN + ReLU + residual (persistent, software grid barrier)
    gather_final_kernel<<<GGRID, 256, 0, stream>>>(
        mix, kpl, row_start, (const int*)tmp, h0, x, gamma, beta, stats, counter);
}

// Round 11
// 185.796 us; speedup vs baseline: 1.5345x; 1.5345x over previous
//
#include <hip/hip_runtime.h>
#include <hip/hip_bf16.h>
#include <math.h>

#define N_NODES 100000
#define N_EDGES 1600000
#define D_FEAT  64
#define BN_EPS  1e-5f

#define NBUCKET 196          // real buckets (dst>>9 in [0,196))
#define NBUCKET_PAD 256
#define BUCKET_SHIFT 9       // 512 nodes per bucket
#define NBLK_E  196          // scatter blocks
#define EPB     8192         // edges per scatter block
#define CCAP    96           // per-(bucket,block) chunk capacity (mean 32)
#define DCAP    14336        // bucket staging cap (mean 8192, sd ~90)
#define GEMM_BLOCKS 1563     // ceil(N_NODES / 64)

typedef __attribute__((ext_vector_type(8))) short bf16x8;
typedef __attribute__((ext_vector_type(4))) float f32x4;

static __device__ __forceinline__ short f2bf(float f) {
    __hip_bfloat16 h = __float2bfloat16(f);
    return __builtin_bit_cast(short, h);
}

// ws layout (byte offsets):
//   0         : mix plane, [N] rows of 192 B: 64 B q-fp8 + 128 B v-bf16 (19,200,000)
//   19200000  : k plane, [N][64] bf16                         (12,800,000)
//   32000000  : stats fp32[128]                               (512)
//   32000512  : counts int[196*196]                           (153,664)
//   32154176  : row_se int2[N]                                (800,000)
//   32954176  : chunks u32[196*196*96] (scatter chunks, then sorted src
//               overlaid per bucket)                          (14,751,744)
//   total 47,705,920

// ---------------------------------------------------------------------------
// Kernel 1 (fused): blocks [0,GEMM_BLOCKS) = four bf16 MFMA linears with
// LDS-repacked coalesced epilogue (q->fp8, v/k->bf16); blocks
// [GEMM_BLOCKS, +NBLK_E) = single-pass edge scatter into fixed-capacity
// per-(bucket,block) chunks (no global scan needed).
// ---------------------------------------------------------------------------
__global__ __launch_bounds__(256) void gemm4_scatter_kernel(
    const float* __restrict__ x,
    const float* __restrict__ Wk, const float* __restrict__ bk,
    const float* __restrict__ Wq, const float* __restrict__ bq,
    const float* __restrict__ Wv, const float* __restrict__ bv,
    const float* __restrict__ Ws, const float* __restrict__ bs,
    unsigned char* __restrict__ mix,    // [N] 192-B rows (q fp8 | v bf16)
    unsigned short* __restrict__ kp,    // [N][64] bf16 bits
    float* __restrict__ h0,             // [N][64] fp32 (== d_out)
    const int* __restrict__ ei,
    int* __restrict__ counts,           // [bucket][block]
    unsigned int* __restrict__ chunks)  // [bucket][block][CCAP]
{
    __shared__ short xs[64 * 64];            // 8 KB staging tile
    __shared__ unsigned short kt[64][68];    // padded repack tiles
    __shared__ unsigned short qt[64][68];
    __shared__ unsigned short vt[64][68];
    __shared__ int hcnt[NBUCKET_PAD];        // scatter cursors

    // ---------------- scatter path ----------------
    if (blockIdx.x >= GEMM_BLOCKS) {
        const int cb = blockIdx.x - GEMM_BLOCKS;
        hcnt[threadIdx.x] = 0;
        __syncthreads();
        const int base = cb * EPB;
        for (int i = threadIdx.x; i < EPB; i += 256) {
            const int e = base + i;
            if (e < N_EDGES) {
                const int s = ei[e];
                const int d = ei[N_EDGES + e];
                const int b = d >> BUCKET_SHIFT;
                const int pos = atomicAdd(&hcnt[b], 1);
                if (pos < CCAP)
                    chunks[((size_t)b * NBLK_E + cb) * CCAP + pos] =
                        ((unsigned int)s << BUCKET_SHIFT) | (unsigned int)(d & 511);
            }
        }
        __syncthreads();
        if (threadIdx.x < NBUCKET)
            counts[threadIdx.x * NBLK_E + cb] = min(hcnt[threadIdx.x], CCAP);
        return;
    }

    // ---------------- GEMM path ----------------
    const int lane = threadIdx.x & 63;
    const int wave = threadIdx.x >> 6;
    const int r0 = blockIdx.x * 64;

    const float* W; const float* b;
    if      (wave == 0) { W = Wk; b = bk; }
    else if (wave == 1) { W = Wq; b = bq; }
    else if (wave == 2) { W = Wv; b = bv; }
    else                { W = Ws; b = bs; }

    const int bcol = lane & 15;
    const int bk0  = (lane >> 4) * 8;
    bf16x8 bfrag[4][2];
    #pragma unroll
    for (int nt = 0; nt < 4; ++nt) {
        #pragma unroll
        for (int ks = 0; ks < 2; ++ks) {
            const float* wp = W + (nt * 16 + bcol) * 64 + ks * 32 + bk0;
            const float4 w0 = *reinterpret_cast<const float4*>(wp);
            const float4 w1 = *reinterpret_cast<const float4*>(wp + 4);
            bf16x8 f;
            f[0] = f2bf(w0.x); f[1] = f2bf(w0.y); f[2] = f2bf(w0.z); f[3] = f2bf(w0.w);
            f[4] = f2bf(w1.x); f[5] = f2bf(w1.y); f[6] = f2bf(w1.z); f[7] = f2bf(w1.w);
            bfrag[nt][ks] = f;
        }
    }
    float biasv[4];
    #pragma unroll
    for (int nt = 0; nt < 4; ++nt) biasv[nt] = b[nt * 16 + bcol];

    {
        const int row = threadIdx.x >> 2;
        const int qd  = threadIdx.x & 3;
        const int grow = r0 + row;
        float4 t0, t1, t2, t3;
        if (grow < N_NODES) {
            const float* xp = x + (size_t)grow * 64 + qd * 16;
            t0 = reinterpret_cast<const float4*>(xp)[0];
            t1 = reinterpret_cast<const float4*>(xp)[1];
            t2 = reinterpret_cast<const float4*>(xp)[2];
            t3 = reinterpret_cast<const float4*>(xp)[3];
        } else {
            t0 = t1 = t2 = t3 = make_float4(0.f, 0.f, 0.f, 0.f);
        }
        bf16x8 u0, u1;
        u0[0] = f2bf(t0.x); u0[1] = f2bf(t0.y); u0[2] = f2bf(t0.z); u0[3] = f2bf(t0.w);
        u0[4] = f2bf(t1.x); u0[5] = f2bf(t1.y); u0[6] = f2bf(t1.z); u0[7] = f2bf(t1.w);
        u1[0] = f2bf(t2.x); u1[1] = f2bf(t2.y); u1[2] = f2bf(t2.z); u1[3] = f2bf(t2.w);
        u1[4] = f2bf(t3.x); u1[5] = f2bf(t3.y); u1[6] = f2bf(t3.z); u1[7] = f2bf(t3.w);
        const int sw = row & 7;
        *reinterpret_cast<bf16x8*>(xs + row * 64 + (((qd * 2)     ^ sw) * 8)) = u0;
        *reinterpret_cast<bf16x8*>(xs + row * 64 + (((qd * 2 + 1) ^ sw) * 8)) = u1;
    }
    __syncthreads();

    f32x4 acc[4][4];
    #pragma unroll
    for (int mt = 0; mt < 4; ++mt)
        #pragma unroll
        for (int nt = 0; nt < 4; ++nt)
            acc[mt][nt] = (f32x4){biasv[nt], biasv[nt], biasv[nt], biasv[nt]};

    const int arow = lane & 15;
    const int ak   = lane >> 4;
    #pragma unroll
    for (int mt = 0; mt < 4; ++mt) {
        const int row = mt * 16 + arow;
        const int sw = row & 7;
        const bf16x8 a0 = *reinterpret_cast<const bf16x8*>(xs + row * 64 + ((ak       ^ sw) * 8));
        const bf16x8 a1 = *reinterpret_cast<const bf16x8*>(xs + row * 64 + (((4 + ak) ^ sw) * 8));
        #pragma unroll
        for (int nt = 0; nt < 4; ++nt) {
            acc[mt][nt] = __builtin_amdgcn_mfma_f32_16x16x32_bf16(
                a0, bfrag[nt][0], acc[mt][nt], 0, 0, 0);
            acc[mt][nt] = __builtin_amdgcn_mfma_f32_16x16x32_bf16(
                a1, bfrag[nt][1], acc[mt][nt], 0, 0, 0);
        }
    }

    // epilogue: waves 0/1/2 stash bf16 results in LDS; wave 3 stores h0 fp32.
    const int crow0 = (lane >> 4) * 4;
    const int ccol  = lane & 15;
    if (wave < 3) {
        unsigned short (*tile)[68] = (wave == 0) ? kt : (wave == 1) ? qt : vt;
        #pragma unroll
        for (int mt = 0; mt < 4; ++mt)
            #pragma unroll
            for (int nt = 0; nt < 4; ++nt)
                #pragma unroll
                for (int r = 0; r < 4; ++r)
                    tile[mt * 16 + crow0 + r][nt * 16 + ccol] =
                        (unsigned short)f2bf(acc[mt][nt][r]);
    } else {
        #pragma unroll
        for (int mt = 0; mt < 4; ++mt)
            #pragma unroll
            for (int nt = 0; nt < 4; ++nt)
                #pragma unroll
                for (int r = 0; r < 4; ++r) {
                    const int grow = r0 + mt * 16 + crow0 + r;
                    if (grow < N_NODES)
                        h0[(size_t)grow * 64 + nt * 16 + ccol] = acc[mt][nt][r];
                }
    }
    __syncthreads();

    // cooperative coalesced flush: thread -> (row, 16-feature segment)
    {
        const int row = threadIdx.x >> 2;
        const int seg = threadIdx.x & 3;
        const int grow = r0 + row;
        if (grow < N_NODES) {
            const int c0 = seg * 16;
            unsigned char* mrow = mix + (size_t)grow * 192;

            // q -> fp8 e4m3 (16 B per seg)
            unsigned int qd[4];
            #pragma unroll
            for (int i = 0; i < 4; ++i) {
                const float f0 = __uint_as_float((unsigned int)qt[row][c0 + 4*i + 0] << 16);
                const float f1 = __uint_as_float((unsigned int)qt[row][c0 + 4*i + 1] << 16);
                const float f2 = __uint_as_float((unsigned int)qt[row][c0 + 4*i + 2] << 16);
                const float f3 = __uint_as_float((unsigned int)qt[row][c0 + 4*i + 3] << 16);
                int p = __builtin_amdgcn_cvt_pk_fp8_f32(f0, f1, 0, false);
                p = __builtin_amdgcn_cvt_pk_fp8_f32(f2, f3, p, true);
                qd[i] = (unsigned int)p;
            }
            *reinterpret_cast<uint4*>(mrow + c0) =
                make_uint4(qd[0], qd[1], qd[2], qd[3]);

            // v -> bf16 (32 B per seg)
            unsigned int vd[8];
            #pragma unroll
            for (int i = 0; i < 8; ++i)
                vd[i] = (unsigned int)vt[row][c0 + 2 * i] |
                        ((unsigned int)vt[row][c0 + 2 * i + 1] << 16);
            uint4* vdst = reinterpret_cast<uint4*>(mrow + 64 + seg * 32);
            vdst[0] = make_uint4(vd[0], vd[1], vd[2], vd[3]);
            vdst[1] = make_uint4(vd[4], vd[5], vd[6], vd[7]);

            // k -> bf16 plane (32 B per seg)
            unsigned int kd[8];
            #pragma unroll
            for (int i = 0; i < 8; ++i)
                kd[i] = (unsigned int)kt[row][c0 + 2 * i] |
                        ((unsigned int)kt[row][c0 + 2 * i + 1] << 16);
            uint4* kdst = reinterpret_cast<uint4*>(kp + (size_t)grow * 64 + c0);
            kdst[0] = make_uint4(kd[0], kd[1], kd[2], kd[3]);
            kdst[1] = make_uint4(kd[4], kd[5], kd[6], kd[7]);
        }
    }
}

// ---------------------------------------------------------------------------
// Per-bucket counting sort: stage chunks to LDS, sort by local dst, emit
// row_se (start,end) and sorted src overlaid on the bucket's chunk region.
// One block per bucket; only this block touches bucket b's region.
// ---------------------------------------------------------------------------
__global__ __launch_bounds__(512) void bucket_sort_kernel(
    const int* __restrict__ counts,
    unsigned int* __restrict__ chunks,
    int2* __restrict__ row_se)
{
    __shared__ unsigned int stage[DCAP];
    __shared__ int hist[512];
    __shared__ int cursor[512];
    __shared__ int cpre[256];
    const int b = blockIdx.x;
    const int t = threadIdx.x;

    // chunk counts + inclusive prefix (Hillis-Steele over 256 slots)
    int myc = 0;
    if (t < 256) {
        myc = (t < NBLK_E) ? counts[b * NBLK_E + t] : 0;
        cpre[t] = myc;
    }
    __syncthreads();
    for (int off = 1; off < 256; off <<= 1) {
        int val = 0;
        if (t < 256 && t >= off) val = cpre[t - off];
        __syncthreads();
        if (t < 256) cpre[t] += val;
        __syncthreads();
    }
    const int total = cpre[255];

    // stage: thread t copies chunk t's edges into compacted LDS
    if (t < NBLK_E && myc > 0) {
        const int dst0 = cpre[t] - myc;
        const unsigned int* src = chunks + ((size_t)b * NBLK_E + t) * CCAP;
        for (int c = 0; c < myc; ++c) {
            const int d = dst0 + c;
            if (d < DCAP) stage[d] = src[c];
        }
    }
    hist[t] = 0;
    __syncthreads();

    int sz = total;
    if (sz > DCAP) sz = DCAP;
    for (int i = t; i < sz; i += 512) atomicAdd(&hist[stage[i] & 511], 1);
    __syncthreads();
    const int myv = hist[t];
    for (int off = 1; off < 512; off <<= 1) {
        const int u = (t >= off) ? hist[t - off] : 0;
        __syncthreads();
        hist[t] += u;
        __syncthreads();
    }
    const int excl = hist[t] - myv;
    const int node = b * 512 + t;
    const int obase = b * NBLK_E * CCAP;   // bucket output base (u32 index)
    if (node < N_NODES)
        row_se[node] = make_int2(obase + excl, obase + excl + myv);
    cursor[t] = excl;
    __syncthreads();

    unsigned int* out = chunks + (size_t)obase;
    for (int i = t; i < sz; i += 512) {
        const unsigned int pk = stage[i];
        const int pos = atomicAdd(&cursor[(int)(pk & 511)], 1);
        out[pos] = pk >> BUCKET_SHIFT;
    }
}

// ---------------------------------------------------------------------------
// Gather: 4 nodes per wave (16 lanes/node, 4 features/lane); mixed-precision
// row gather (q fp8 + v bf16, 192 B/row); row_se int2; fused BN stats.
// src clamped (padding gaps in chunks are uninitialized).
// ---------------------------------------------------------------------------
static __device__ __forceinline__ void edge4(
    float4& acc, const float4& kf, unsigned int qb, uint2 vb)
{
    const float q0 = __builtin_amdgcn_cvt_f32_fp8(qb, 0);
    const float q1 = __builtin_amdgcn_cvt_f32_fp8(qb, 1);
    const float q2 = __builtin_amdgcn_cvt_f32_fp8(qb, 2);
    const float q3 = __builtin_amdgcn_cvt_f32_fp8(qb, 3);
    const float v0 = __uint_as_float(vb.x << 16);
    const float v1 = __uint_as_float(vb.x & 0xffff0000u);
    const float v2 = __uint_as_float(vb.y << 16);
    const float v3 = __uint_as_float(vb.y & 0xffff0000u);
    acc.x = fmaf(__builtin_amdgcn_rcpf(1.0f + __expf(-(kf.x + q0))), v0, acc.x);
    acc.y = fmaf(__builtin_amdgcn_rcpf(1.0f + __expf(-(kf.y + q1))), v1, acc.y);
    acc.z = fmaf(__builtin_amdgcn_rcpf(1.0f + __expf(-(kf.z + q2))), v2, acc.z);
    acc.w = fmaf(__builtin_amdgcn_rcpf(1.0f + __expf(-(kf.w + q3))), v3, acc.w);
}

__global__ __launch_bounds__(256, 4) void gather_kernel(
    const unsigned char* __restrict__ mix,
    const unsigned short* __restrict__ kp,
    const int2* __restrict__ row_se,
    const unsigned int* __restrict__ sorted_src,
    float* __restrict__ h0, float* __restrict__ stats)
{
    const int lane = threadIdx.x & 63;
    const int sub  = lane >> 4;
    const int l    = lane & 15;
    const int wave = threadIdx.x >> 6;

    float4 lsum = make_float4(0.f, 0.f, 0.f, 0.f);
    float4 lsq  = make_float4(0.f, 0.f, 0.f, 0.f);

    const int quad0  = blockIdx.x * 4 + wave;
    const int qstride = gridDim.x * 4;
    const int nquads = N_NODES / 4;

    for (int quad = quad0; quad < nquads; quad += qstride) {
        const int n = quad * 4 + sub;
        const int2 se = row_se[n];
        const int base = se.x;
        const int end  = se.y;
        const int deg  = end - base;

        int m1 = max(deg, __shfl_xor(deg, 16));
        const int maxdeg = max(m1, __shfl_xor(m1, 32));

        const ushort4 kr = *reinterpret_cast<const ushort4*>(kp + (size_t)n * 64 + 4 * l);
        float4 kf;
        kf.x = __uint_as_float((unsigned int)kr.x << 16);
        kf.y = __uint_as_float((unsigned int)kr.y << 16);
        kf.z = __uint_as_float((unsigned int)kr.z << 16);
        kf.w = __uint_as_float((unsigned int)kr.w << 16);
        float4 acc = *reinterpret_cast<const float4*>(h0 + (size_t)n * 64 + 4 * l);

        const int safe_last = max(end - 1, 0);

        for (int t = 0; t < maxdeg; t += 4) {
            const int i0 = min(base + t + 0, safe_last);
            const int i1 = min(base + t + 1, safe_last);
            const int i2 = min(base + t + 2, safe_last);
            const int i3 = min(base + t + 3, safe_last);
            // clamp src: padding slots hold uninitialized data
            const int s0 = min((int)sorted_src[i0], N_NODES - 1);
            const int s1 = min((int)sorted_src[i1], N_NODES - 1);
            const int s2 = min((int)sorted_src[i2], N_NODES - 1);
            const int s3 = min((int)sorted_src[i3], N_NODES - 1);
            const size_t r0 = (size_t)s0 * 192;
            const size_t r1 = (size_t)s1 * 192;
            const size_t r2 = (size_t)s2 * 192;
            const size_t r3 = (size_t)s3 * 192;
            const unsigned int qb0 = *reinterpret_cast<const unsigned int*>(mix + r0 + 4 * l);
            const unsigned int qb1 = *reinterpret_cast<const unsigned int*>(mix + r1 + 4 * l);
            const unsigned int qb2 = *reinterpret_cast<const unsigned int*>(mix + r2 + 4 * l);
            const unsigned int qb3 = *reinterpret_cast<const unsigned int*>(mix + r3 + 4 * l);
            uint2 vb0 = *reinterpret_cast<const uint2*>(mix + r0 + 64 + 8 * l);
            uint2 vb1 = *reinterpret_cast<const uint2*>(mix + r1 + 64 + 8 * l);
            uint2 vb2 = *reinterpret_cast<const uint2*>(mix + r2 + 64 + 8 * l);
            uint2 vb3 = *reinterpret_cast<const uint2*>(mix + r3 + 64 + 8 * l);
            const bool m0 = (t + 0) < deg, m1b = (t + 1) < deg,
                       m2 = (t + 2) < deg, m3 = (t + 3) < deg;
            vb0.x = m0 ? vb0.x : 0u;  vb0.y = m0 ? vb0.y : 0u;
            vb1.x = m1b ? vb1.x : 0u; vb1.y = m1b ? vb1.y : 0u;
            vb2.x = m2 ? vb2.x : 0u;  vb2.y = m2 ? vb2.y : 0u;
            vb3.x = m3 ? vb3.x : 0u;  vb3.y = m3 ? vb3.y : 0u;

            edge4(acc, kf, qb0, vb0);
            edge4(acc, kf, qb1, vb1);
            edge4(acc, kf, qb2, vb2);
            edge4(acc, kf, qb3, vb3);
        }

        *reinterpret_cast<float4*>(h0 + (size_t)n * 64 + 4 * l) = acc;
        lsum.x += acc.x; lsum.y += acc.y; lsum.z += acc.z; lsum.w += acc.w;
        lsq.x += acc.x * acc.x; lsq.y += acc.y * acc.y;
        lsq.z += acc.z * acc.z; lsq.w += acc.w * acc.w;
    }

    __shared__ float bsum[64];
    __shared__ float bsq[64];
    if (threadIdx.x < 64) { bsum[threadIdx.x] = 0.f; bsq[threadIdx.x] = 0.f; }
    __syncthreads();
    atomicAdd(&bsum[4 * l + 0], lsum.x); atomicAdd(&bsq[4 * l + 0], lsq.x);
    atomicAdd(&bsum[4 * l + 1], lsum.y); atomicAdd(&bsq[4 * l + 1], lsq.y);
    atomicAdd(&bsum[4 * l + 2], lsum.z); atomicAdd(&bsq[4 * l + 2], lsq.z);
    atomicAdd(&bsum[4 * l + 3], lsum.w); atomicAdd(&bsq[4 * l + 3], lsq.w);
    __syncthreads();
    if (threadIdx.x < 64) {
        atomicAdd(&stats[threadIdx.x], bsum[threadIdx.x]);
        atomicAdd(&stats[64 + threadIdx.x], bsq[threadIdx.x]);
    }
}

// ---------------------------------------------------------------------------
// Final: BN + ReLU + residual; quad mapping mirrors gather; float4 everywhere.
// ---------------------------------------------------------------------------
__global__ __launch_bounds__(256) void final_kernel(
    float* __restrict__ h0, const float* __restrict__ x,
    const float* __restrict__ stats,
    const float* __restrict__ gamma, const float* __restrict__ beta)
{
    const int lane = threadIdx.x & 63;
    const int sub  = lane >> 4;
    const int l    = lane & 15;
    const int wave = threadIdx.x >> 6;

    const float invN = 1.0f / (float)N_NODES;
    const float4 s1 = *reinterpret_cast<const float4*>(stats + 4 * l);
    const float4 s2 = *reinterpret_cast<const float4*>(stats + 64 + 4 * l);
    const float4 g  = *reinterpret_cast<const float4*>(gamma + 4 * l);
    const float4 bt = *reinterpret_cast<const float4*>(beta + 4 * l);
    float4 mean, a;
    mean.x = s1.x * invN; mean.y = s1.y * invN;
    mean.z = s1.z * invN; mean.w = s1.w * invN;
    a.x = rsqrtf(s2.x * invN - mean.x * mean.x + BN_EPS) * g.x;
    a.y = rsqrtf(s2.y * invN - mean.y * mean.y + BN_EPS) * g.y;
    a.z = rsqrtf(s2.z * invN - mean.z * mean.z + BN_EPS) * g.z;
    a.w = rsqrtf(s2.w * invN - mean.w * mean.w + BN_EPS) * g.w;

    const int quad0  = blockIdx.x * 4 + wave;
    const int qstride = gridDim.x * 4;
    const int nquads = N_NODES / 4;

    for (int quad = quad0; quad < nquads; quad += qstride) {
        const int n = quad * 4 + sub;
        const size_t off = (size_t)n * 64 + 4 * l;
        const float4 h  = *reinterpret_cast<const float4*>(h0 + off);
        const float4 xx = *reinterpret_cast<const float4*>(x + off);
        float4 y;
        y.x = fmaxf((h.x - mean.x) * a.x + bt.x, 0.f) + xx.x;
        y.y = fmaxf((h.y - mean.y) * a.y + bt.y, 0.f) + xx.y;
        y.z = fmaxf((h.z - mean.z) * a.z + bt.z, 0.f) + xx.z;
        y.w = fmaxf((h.w - mean.w) * a.w + bt.w, 0.f) + xx.w;
        *reinterpret_cast<float4*>(h0 + off) = y;
    }
}

// ---------------------------------------------------------------------------
extern "C" void kernel_launch(void* const* d_in, const int* in_sizes, int n_in,
                              void* d_out, int out_size, void* d_ws, size_t ws_size,
                              hipStream_t stream)
{
    const float* x     = (const float*)d_in[0];
    const int*   ei    = (const int*)d_in[1];
    const float* Wk    = (const float*)d_in[2];
    const float* bk    = (const float*)d_in[3];
    const float* Wq    = (const float*)d_in[4];
    const float* bq    = (const float*)d_in[5];
    const float* Wv    = (const float*)d_in[6];
    const float* bv    = (const float*)d_in[7];
    const float* Ws    = (const float*)d_in[8];
    const float* bs    = (const float*)d_in[9];
    const float* gamma = (const float*)d_in[10];
    const float* beta  = (const float*)d_in[11];

    char* w = (char*)d_ws;
    unsigned char*  mix  = (unsigned char*)w;               // 19.2 MB
    unsigned short* kpl  = (unsigned short*)(w + 19200000); // 12.8 MB
    float* stats      = (float*)(w + 32000000);             // 512 B
    int*   counts     = (int*)  (w + 32000512);             // 153,664 B
    int2*  row_se     = (int2*) (w + 32154176);             // 800,000 B
    unsigned int* chunks = (unsigned int*)(w + 32954176);   // 14.75 MB

    float* h0 = (float*)d_out;

    hipMemsetAsync(stats, 0, 512, stream);

    // fused: MFMA linears (blocks 0..1562) + single-pass chunk scatter
    gemm4_scatter_kernel<<<GEMM_BLOCKS + NBLK_E, 256, 0, stream>>>(
        x, Wk, bk, Wq, bq, Wv, bv, Ws, bs, mix, kpl, h0, ei, counts, chunks);

    // per-bucket counting sort -> row_se + sorted src (overlaid)
    bucket_sort_kernel<<<NBUCKET, 512, 0, stream>>>(counts, chunks, row_se);

    // gather-side aggregation + fused BN stats
    gather_kernel<<<2084, 256, 0, stream>>>(
        mix, kpl, row_se, chunks, h0, stats);

    // normalize + relu + residual, in place
    final_kernel<<<2084, 256, 0, stream>>>(h0, x, stats, gamma, beta);
}